// Round 1
// baseline (327.663 us; speedup 1.0000x reference)
//
#include <hip/hip_runtime.h>
#include <cstdint>
#include <math.h>

#define BB 256
#define CC 64
#define TT 4000
#define NHID 64
#define NOUT 64
#define NMLP (NOUT*(CC+1))  // 4160

// ---------------- K1: per-(b,c) log-variance over T ----------------
// grid (4, 256), block 256. Each wave handles 4 channel rows.
__global__ __launch_bounds__(256) void k_var(const float* __restrict__ x,
                                             float* __restrict__ feats) {
    int b    = blockIdx.y;
    int wave = threadIdx.x >> 6;
    int lane = threadIdx.x & 63;
    int cbase = blockIdx.x * 16 + wave * 4;
    const float* xb = x + (size_t)b * (CC * TT);
    #pragma unroll
    for (int k = 0; k < 4; ++k) {
        int c = cbase + k;
        const float4* row = (const float4*)(xb + (size_t)c * TT);
        float s = 0.f, ss = 0.f;
        for (int i = lane; i < TT / 4; i += 64) {   // 1000 float4s
            float4 v = row[i];
            s  += v.x + v.y + v.z + v.w;
            ss += v.x * v.x + v.y * v.y + v.z * v.z + v.w * v.w;
        }
        #pragma unroll
        for (int off = 32; off > 0; off >>= 1) {
            s  += __shfl_down(s, off);
            ss += __shfl_down(ss, off);
        }
        if (lane == 0) {
            float var = (ss - s * s / (float)TT) / (float)(TT - 1);
            float f = logf(var);
            if (isinf(f) && f < 0.f) f = 0.f;   // jnp.where(isneginf, 0, .)
            feats[b * CC + c] = f;
        }
    }
}

// ---------------- K2: MLP hypernetwork + transpose of W ----------------
// grid 256, block 256. Produces wsB[b][o] (bias) and wsW[b][c][o] (transposed W).
__global__ __launch_bounds__(256) void k_mlp(const float* __restrict__ feats,
                                             const float* __restrict__ W1,
                                             const float* __restrict__ b1,
                                             const float* __restrict__ W2,
                                             const float* __restrict__ b2,
                                             float* __restrict__ wsW,
                                             float* __restrict__ wsB) {
    int b = blockIdx.x;
    int tid = threadIdx.x;
    __shared__ float fs[CC];
    __shared__ float hs[NHID];
    if (tid < CC) fs[tid] = feats[b * CC + tid];
    __syncthreads();
    if (tid < NHID) {
        float v = b1[tid];
        #pragma unroll 8
        for (int c = 0; c < CC; ++c) v = fmaf(fs[c], W1[c * NHID + tid], v);
        hs[tid] = v > 0.f ? v : 0.f;
    }
    __syncthreads();
    for (int j = tid; j < NMLP; j += 256) {
        float v = b2[j];
        #pragma unroll 8
        for (int c = 0; c < NHID; ++c) v = fmaf(hs[c], W2[c * NMLP + j], v);
        if (j < NOUT) {
            wsB[b * NOUT + j] = v;
        } else {
            int k = j - NOUT;
            int o = k >> 6, c2 = k & 63;          // mlp_out[64 + o*64 + c] = W[o][c]
            wsW[(size_t)b * 4096 + c2 * 64 + o] = v;  // store transposed [c][o]
        }
    }
}

// ---------------- K3: out[b,o,t] = sum_c W[o,c]*x[b,c,t] + bias[o] ----------------
// grid (16, 256), block 256. W staged in LDS as [c][o] (float4-readable).
__global__ __launch_bounds__(256) void k_apply(const float* __restrict__ x,
                                               const float* __restrict__ wsW,
                                               const float* __restrict__ wsB,
                                               float* __restrict__ out) {
    int b = blockIdx.y;
    int tid = threadIdx.x;
    __shared__ float Wl[4096];
    __shared__ float bl[64];
    const float* wb = wsW + (size_t)b * 4096;
    #pragma unroll
    for (int i = 0; i < 16; ++i) Wl[i * 256 + tid] = wb[i * 256 + tid];
    if (tid < 64) bl[tid] = wsB[b * 64 + tid];
    __syncthreads();

    int t = blockIdx.x * 256 + tid;
    if (t >= TT) return;

    float acc[64];
    #pragma unroll
    for (int o = 0; o < 64; ++o) acc[o] = bl[o];

    const float* xb = x + (size_t)b * (CC * TT) + t;
    for (int c = 0; c < CC; ++c) {
        float xv = xb[(size_t)c * TT];
        const float4* wrow = (const float4*)&Wl[c * 64];
        #pragma unroll
        for (int o4 = 0; o4 < 16; ++o4) {
            float4 w = wrow[o4];
            acc[o4 * 4 + 0] = fmaf(w.x, xv, acc[o4 * 4 + 0]);
            acc[o4 * 4 + 1] = fmaf(w.y, xv, acc[o4 * 4 + 1]);
            acc[o4 * 4 + 2] = fmaf(w.z, xv, acc[o4 * 4 + 2]);
            acc[o4 * 4 + 3] = fmaf(w.w, xv, acc[o4 * 4 + 3]);
        }
    }

    float* ob = out + (size_t)b * (NOUT * TT) + t;
    #pragma unroll
    for (int o = 0; o < 64; ++o) ob[(size_t)o * TT] = acc[o];
}

extern "C" void kernel_launch(void* const* d_in, const int* in_sizes, int n_in,
                              void* d_out, int out_size, void* d_ws, size_t ws_size,
                              hipStream_t stream) {
    const float* x  = (const float*)d_in[0];
    const float* W1 = (const float*)d_in[1];
    const float* b1 = (const float*)d_in[2];
    const float* W2 = (const float*)d_in[3];
    const float* b2 = (const float*)d_in[4];
    float* out = (float*)d_out;
    float* ws  = (float*)d_ws;

    float* feats = ws;            // 256*64      = 16384 floats
    float* wsB   = ws + 16384;    // 256*64      = 16384 floats
    float* wsW   = ws + 32768;    // 256*4096    = 1048576 floats

    k_var<<<dim3(4, 256), 256, 0, stream>>>(x, feats);
    k_mlp<<<256, 256, 0, stream>>>(feats, W1, b1, W2, b2, wsW, wsB);
    k_apply<<<dim3(16, 256), 256, 0, stream>>>(x, wsW, wsB, out);
}

// Round 2
// 307.966 us; speedup vs baseline: 1.0640x; 1.0640x over previous
//
#include <hip/hip_runtime.h>
#include <cstdint>
#include <math.h>

#define BB 256
#define CC 64
#define TT 4000
#define NHID 64
#define NOUT 64
#define NMLP (NOUT*(CC+1))  // 4160

// ---------------- K1: per-(b,c) log-variance over T ----------------
// grid (16, 256), block 256 (4 waves). One wave per channel row.
__global__ __launch_bounds__(256) void k_var(const float* __restrict__ x,
                                             float* __restrict__ feats) {
    int b    = blockIdx.y;
    int wave = threadIdx.x >> 6;
    int lane = threadIdx.x & 63;
    int c    = blockIdx.x * 4 + wave;
    const float4* row = (const float4*)(x + (size_t)b * (CC * TT) + (size_t)c * TT);
    float s = 0.f, ss = 0.f;
    for (int i = lane; i < TT / 4; i += 64) {   // 1000 float4s
        float4 v = row[i];
        s  += v.x + v.y + v.z + v.w;
        ss += v.x * v.x + v.y * v.y + v.z * v.z + v.w * v.w;
    }
    #pragma unroll
    for (int off = 32; off > 0; off >>= 1) {
        s  += __shfl_down(s, off);
        ss += __shfl_down(ss, off);
    }
    if (lane == 0) {
        float var = (ss - s * s / (float)TT) / (float)(TT - 1);
        float f = logf(var);
        if (isinf(f) && f < 0.f) f = 0.f;   // jnp.where(isneginf, 0, .)
        feats[b * CC + c] = f;
    }
}

// ---------------- K2: MLP hypernetwork + transpose of W ----------------
// grid 256, block 256. Produces wsB[b][o] (bias) and wsW[b][c][o] (transposed W).
__global__ __launch_bounds__(256) void k_mlp(const float* __restrict__ feats,
                                             const float* __restrict__ W1,
                                             const float* __restrict__ b1,
                                             const float* __restrict__ W2,
                                             const float* __restrict__ b2,
                                             float* __restrict__ wsW,
                                             float* __restrict__ wsB) {
    int b = blockIdx.x;
    int tid = threadIdx.x;
    __shared__ float fs[CC];
    __shared__ float hs[NHID];
    if (tid < CC) fs[tid] = feats[b * CC + tid];
    __syncthreads();
    if (tid < NHID) {
        float v = b1[tid];
        #pragma unroll 8
        for (int c = 0; c < CC; ++c) v = fmaf(fs[c], W1[c * NHID + tid], v);
        hs[tid] = v > 0.f ? v : 0.f;
    }
    __syncthreads();
    for (int j = tid; j < NMLP; j += 256) {
        float v = b2[j];
        #pragma unroll 8
        for (int c = 0; c < NHID; ++c) v = fmaf(hs[c], W2[c * NMLP + j], v);
        if (j < NOUT) {
            wsB[b * NOUT + j] = v;
        } else {
            int k = j - NOUT;
            int o = k >> 6, c2 = k & 63;          // mlp_out[64 + o*64 + c] = W[o][c]
            wsW[(size_t)b * 4096 + c2 * 64 + o] = v;  // store transposed [c][o]
        }
    }
}

// ---------------- K3: out[b,o,t] = sum_c W[o,c]*x[b,c,t] + bias[o] ----------------
// grid (16, 256), block 256. W/bias are block-uniform -> uniform global reads
// (scalarized to s_load by the compiler); no LDS at all. 1 coalesced x load
// + 64 v_fmac(sgpr, vgpr) per c.
__global__ __launch_bounds__(256) void k_apply(const float* __restrict__ x,
                                               const float* __restrict__ wsW,
                                               const float* __restrict__ wsB,
                                               float* __restrict__ out) {
    int b = blockIdx.y;
    int tid = threadIdx.x;
    int t = blockIdx.x * 256 + tid;
    bool valid = t < TT;
    int tc = valid ? t : (TT - 1);

    const float* wb = wsW + (size_t)b * 4096;   // uniform
    const float* bb = wsB + (size_t)b * 64;     // uniform

    float acc[64];
    #pragma unroll
    for (int o = 0; o < 64; ++o) acc[o] = bb[o];

    const float* xb = x + (size_t)b * (CC * TT) + tc;
    #pragma unroll 2
    for (int c = 0; c < CC; ++c) {
        float xv = xb[(size_t)c * TT];
        const float* wrow = wb + c * 64;        // uniform row
        #pragma unroll
        for (int o = 0; o < 64; ++o) acc[o] = fmaf(wrow[o], xv, acc[o]);
    }

    if (!valid) return;
    float* ob = out + (size_t)b * (NOUT * TT) + t;
    #pragma unroll
    for (int o = 0; o < 64; ++o) ob[(size_t)o * TT] = acc[o];
}

extern "C" void kernel_launch(void* const* d_in, const int* in_sizes, int n_in,
                              void* d_out, int out_size, void* d_ws, size_t ws_size,
                              hipStream_t stream) {
    const float* x  = (const float*)d_in[0];
    const float* W1 = (const float*)d_in[1];
    const float* b1 = (const float*)d_in[2];
    const float* W2 = (const float*)d_in[3];
    const float* b2 = (const float*)d_in[4];
    float* out = (float*)d_out;
    float* ws  = (float*)d_ws;

    float* feats = ws;            // 256*64      = 16384 floats
    float* wsB   = ws + 16384;    // 256*64      = 16384 floats
    float* wsW   = ws + 32768;    // 256*4096    = 1048576 floats

    k_var<<<dim3(16, 256), 256, 0, stream>>>(x, feats);
    k_mlp<<<256, 256, 0, stream>>>(feats, W1, b1, W2, b2, wsW, wsB);
    k_apply<<<dim3(16, 256), 256, 0, stream>>>(x, wsW, wsB, out);
}